// Round 5
// baseline (138.054 us; speedup 1.0000x reference)
//
#include <hip/hip_runtime.h>

typedef __attribute__((ext_vector_type(8))) short short8;
typedef __attribute__((ext_vector_type(4))) float float4v;

__device__ inline float bf2f(ushort u) {
    unsigned v = ((unsigned)u) << 16;
    return __builtin_bit_cast(float, v);
}
__device__ inline ushort f2bf(float f) {
    unsigned u = __builtin_bit_cast(unsigned, f);
    u += 0x7FFFu + ((u >> 16) & 1u);   // RNE
    return (ushort)(u >> 16);
}

// async global->LDS, 16B per lane; LDS dest = wave-uniform base + lane*16
__device__ inline void gload_lds16(const ushort* g, ushort* l) {
    __builtin_amdgcn_global_load_lds(
        (const __attribute__((address_space(1))) unsigned int*)g,
        (__attribute__((address_space(3))) unsigned int*)l,
        16, 0, 0);
}

// ---------------------------------------------------------------------------
// Kernel 1: prep = convert_hs (blocks 0..1023) + transpose_w (blocks 1024..1535)
// ---------------------------------------------------------------------------
__global__ __launch_bounds__(256) void prep(
    const float* __restrict__ hs, ushort* __restrict__ hsb,
    const float* __restrict__ Wq, const float* __restrict__ Wv,
    ushort* __restrict__ Wt) {
    __shared__ ushort tile[64][68];
    if (blockIdx.x < 1024) {
        const size_t base = ((size_t)blockIdx.x * 256 + threadIdx.x) * 16;
        union { ushort u[16]; uint4 v[2]; } o;
#pragma unroll
        for (int q = 0; q < 4; ++q) {
            float4v f = *(const float4v*)(hs + base + q * 4);
#pragma unroll
            for (int j = 0; j < 4; ++j) o.u[q * 4 + j] = f2bf(f[j]);
        }
        *(uint4*)(hsb + base)     = o.v[0];
        *(uint4*)(hsb + base + 8) = o.v[1];
        return;
    }
    const int idx = blockIdx.x - 1024;
    const int z = idx >> 8, yy = (idx >> 4) & 15, xx = idx & 15;
    const float* W = z ? Wv : Wq;
    ushort* Wto    = Wt + (z ? (size_t)1024 * 1024 : 0);
    const int k0 = yy * 64, n0 = xx * 64;
    const int tid = threadIdx.x;
    const int rr = tid >> 4;          // 0..15
    const int cc = (tid & 15) * 4;    // 0..60
    union U4 { ushort u[4]; uint2 v; };
#pragma unroll
    for (int i = 0; i < 4; ++i) {
        int row = rr + i * 16;
        float4v f = *(const float4v*)(W + (size_t)(k0 + row) * 1024 + n0 + cc);
        U4 x;
#pragma unroll
        for (int j = 0; j < 4; ++j) x.u[j] = f2bf(f[j]);
        *(uint2*)&tile[row][cc] = x.v;
    }
    __syncthreads();
#pragma unroll
    for (int i = 0; i < 4; ++i) {
        int row = rr + i * 16;        // n within tile
        U4 o;
#pragma unroll
        for (int j = 0; j < 4; ++j) o.u[j] = tile[cc + j][row];
        *(uint2*)(Wto + (size_t)(n0 + row) * 1024 + k0 + cc) = o.v;
    }
}

// ---------------------------------------------------------------------------
// Kernel 2: fused Q|V GEMM — m201-style 4-phase-per-K-tile schedule.
//   Per phase: {ds_read subtile || gload_lds stage issues} -> sched pin ->
//   s_barrier -> lgkmcnt(0) -> setprio(1) -> 8-MFMA quadrant -> setprio(0)
//   -> s_barrier. Counted vmcnt(6) once per K-tile (never 0 in main loop).
//   Quadrants: Q00(A01,B01) Q01(+B23) Q10(+A23) Q11(no reads, fused in ph3).
//   BM=128, BN=256, BK=64; 512 thr = 8 waves (2M x 4N), 64x64 per wave.
//   LDS: 3 x 48KB buffers, depth-2 prefetch; T2 XOR swizzle via inverse-
//   swizzled global source; XCD-aware remap (n-panel == XCD).
// ---------------------------------------------------------------------------
__global__ __launch_bounds__(512, 2) void qv_gemm(
    const ushort* __restrict__ hsb, const ushort* __restrict__ Wt,
    const float* __restrict__ bq, const float* __restrict__ bv,
    ushort* __restrict__ q_ws, ushort* __restrict__ v_ws) {
    __shared__ ushort smem[73728];                 // 3 * 49152 B
    const int wg = blockIdx.x;                     // 0..255
    const int n0 = (wg & 7) * 256;                 // XCD id (round-robin) -> B panel
    const int m0 = (wg >> 3) * 128;
    const int tid  = threadIdx.x;
    const int wid  = tid >> 6, lane = tid & 63;
    const int quad = lane >> 4, l16 = lane & 15;
    const int wm = (wid >> 2) * 64;                // 0 / 64
    const int wn = (wid & 3) * 64;                 // 0 / 64 / 128 / 192
    const int srow8 = tid >> 3;                    // 0..63 (rows per 8KB round)
    const int scb   = (tid & 7) * 16;              // phys chunk byte 0..112

    auto stage = [&](int ktt, int bi, int r) {
        if (r < 2) {
            int row = r * 64 + srow8;                       // A row 0..127
            int sb  = scb ^ ((row & 7) << 4);               // inverse swizzle
            gload_lds16(hsb + (size_t)(m0 + row) * 1024 + ktt * 64 + (sb >> 1),
                        (ushort*)((char*)smem + bi * 49152 + r * 8192 + wid * 1024));
        } else {
            int row = (r - 2) * 64 + srow8;                 // B row 0..255
            int sb  = scb ^ ((row & 7) << 4);
            gload_lds16(Wt + (size_t)(n0 + row) * 1024 + ktt * 64 + (sb >> 1),
                        (ushort*)((char*)smem + bi * 49152 + 16384 + (r - 2) * 8192 + wid * 1024));
        }
    };

    float4v acc[4][4] = {};

#pragma unroll
    for (int r = 0; r < 6; ++r) stage(0, 0, r);
#pragma unroll
    for (int r = 0; r < 6; ++r) stage(1, 1, r);

    int bi = 0;
    for (int ktt = 0; ktt < 16; ++ktt) {
        const char* Ab = (const char*)smem + bi * 49152;
        const char* Bb = Ab + 16384;
        const int kn = ktt + 2;
        const int b2 = (bi + 2 >= 3) ? bi - 1 : bi + 2;
        const bool pf = (kn < 16);

        // ---- K-tile entry: tile ktt resident; tile ktt+1's 6 stay in flight
        if (ktt < 15) asm volatile("s_waitcnt vmcnt(6)" ::: "memory");
        else          asm volatile("s_waitcnt vmcnt(0)" ::: "memory");
        __builtin_amdgcn_s_barrier();
        __builtin_amdgcn_sched_barrier(0);

        short8 af[4][2], bfr[4][2];

        // ======== phase 0: read A01+B01 (8) || stage r0,r1 -> MFMA Q00 ====
#pragma unroll
        for (int mt = 0; mt < 2; ++mt) {
            int ar = wm + mt * 16 + l16;
            int sw = (ar & 7) << 4;
            af[mt][0] = *(const short8*)(Ab + ar * 128 + ((quad * 16) ^ sw));
            af[mt][1] = *(const short8*)(Ab + ar * 128 + (((4 + quad) * 16) ^ sw));
        }
#pragma unroll
        for (int nt = 0; nt < 2; ++nt) {
            int br = wn + nt * 16 + l16;
            int sw = (br & 7) << 4;
            bfr[nt][0] = *(const short8*)(Bb + br * 128 + ((quad * 16) ^ sw));
            bfr[nt][1] = *(const short8*)(Bb + br * 128 + (((4 + quad) * 16) ^ sw));
        }
        if (pf) { stage(kn, b2, 0); stage(kn, b2, 1); }
        __builtin_amdgcn_sched_barrier(0);
        __builtin_amdgcn_s_barrier();
        asm volatile("s_waitcnt lgkmcnt(0)" ::: "memory");
        __builtin_amdgcn_sched_barrier(0);
        __builtin_amdgcn_s_setprio(1);
#pragma unroll
        for (int ks = 0; ks < 2; ++ks)
#pragma unroll
            for (int mt = 0; mt < 2; ++mt)
#pragma unroll
                for (int nt = 0; nt < 2; ++nt)
                    acc[mt][nt] = __builtin_amdgcn_mfma_f32_16x16x32_bf16(
                        af[mt][ks], bfr[nt][ks], acc[mt][nt], 0, 0, 0);
        __builtin_amdgcn_s_setprio(0);
        __builtin_amdgcn_sched_barrier(0);
        __builtin_amdgcn_s_barrier();

        // ======== phase 1: read B23 (4) || stage r2,r3 -> MFMA Q01 ========
#pragma unroll
        for (int nt = 2; nt < 4; ++nt) {
            int br = wn + nt * 16 + l16;
            int sw = (br & 7) << 4;
            bfr[nt][0] = *(const short8*)(Bb + br * 128 + ((quad * 16) ^ sw));
            bfr[nt][1] = *(const short8*)(Bb + br * 128 + (((4 + quad) * 16) ^ sw));
        }
        if (pf) { stage(kn, b2, 2); stage(kn, b2, 3); }
        __builtin_amdgcn_sched_barrier(0);
        __builtin_amdgcn_s_barrier();
        asm volatile("s_waitcnt lgkmcnt(0)" ::: "memory");
        __builtin_amdgcn_sched_barrier(0);
        __builtin_amdgcn_s_setprio(1);
#pragma unroll
        for (int ks = 0; ks < 2; ++ks)
#pragma unroll
            for (int mt = 0; mt < 2; ++mt)
#pragma unroll
                for (int nt = 2; nt < 4; ++nt)
                    acc[mt][nt] = __builtin_amdgcn_mfma_f32_16x16x32_bf16(
                        af[mt][ks], bfr[nt][ks], acc[mt][nt], 0, 0, 0);
        __builtin_amdgcn_s_setprio(0);
        __builtin_amdgcn_sched_barrier(0);
        __builtin_amdgcn_s_barrier();

        // ======== phase 2: read A23 (4) || stage r4,r5 -> MFMA Q10 ========
#pragma unroll
        for (int mt = 2; mt < 4; ++mt) {
            int ar = wm + mt * 16 + l16;
            int sw = (ar & 7) << 4;
            af[mt][0] = *(const short8*)(Ab + ar * 128 + ((quad * 16) ^ sw));
            af[mt][1] = *(const short8*)(Ab + ar * 128 + (((4 + quad) * 16) ^ sw));
        }
        if (pf) { stage(kn, b2, 4); stage(kn, b2, 5); }
        __builtin_amdgcn_sched_barrier(0);
        __builtin_amdgcn_s_barrier();
        asm volatile("s_waitcnt lgkmcnt(0)" ::: "memory");
        __builtin_amdgcn_sched_barrier(0);
        __builtin_amdgcn_s_setprio(1);
#pragma unroll
        for (int ks = 0; ks < 2; ++ks)
#pragma unroll
            for (int mt = 2; mt < 4; ++mt)
#pragma unroll
                for (int nt = 0; nt < 2; ++nt)
                    acc[mt][nt] = __builtin_amdgcn_mfma_f32_16x16x32_bf16(
                        af[mt][ks], bfr[nt][ks], acc[mt][nt], 0, 0, 0);

        // ======== phase 3 (fused): MFMA Q11, no new reads ========
#pragma unroll
        for (int ks = 0; ks < 2; ++ks)
#pragma unroll
            for (int mt = 2; mt < 4; ++mt)
#pragma unroll
                for (int nt = 2; nt < 4; ++nt)
                    acc[mt][nt] = __builtin_amdgcn_mfma_f32_16x16x32_bf16(
                        af[mt][ks], bfr[nt][ks], acc[mt][nt], 0, 0, 0);
        __builtin_amdgcn_s_setprio(0);

        bi = (bi + 1 >= 3) ? 0 : bi + 1;
    }

#pragma unroll
    for (int mt = 0; mt < 4; ++mt) {
#pragma unroll
        for (int nt = 0; nt < 4; ++nt) {
            int coln = n0 + wn + nt * 16 + l16;
            bool isq = coln < 1024;
            int c2 = isq ? coln : coln - 1024;
            float bsv = isq ? bq[c2] : bv[c2];
            ushort* outp = isq ? q_ws : v_ws;
            int hh = c2 >> 6, dd = c2 & 63;
#pragma unroll
            for (int reg = 0; reg < 4; ++reg) {
                int r = m0 + wm + mt * 16 + quad * 4 + reg;
                int bb = r >> 11, s = r & 2047;
                outp[(((size_t)bb * 16 + hh) * 2048 + s) * 64 + dd] =
                    f2bf(acc[mt][nt][reg] + bsv);
            }
        }
    }
}

// strided-loop slot macros (static register slots, rule #20)
#define SISSUE(As, Bs, Ms, idx) { const ushort* kr_ = q_ws + srbase + ((size_t)(idx) << 13); \
    As = *(const uint4*)kr_; Bs = *(const uint4*)(kr_ + 8); Ms = amask[amrow + ((idx) << 7)]; }
#define SCONS(As, Bs, Ms, kk) { union { uint4 v; ushort u[8]; } t0_, t1_; t0_.v = As; t1_.v = Bs; \
    float p_ = 0.f; \
    _Pragma("unroll") for (int jj = 0; jj < 8; ++jj) p_ += qv[jj] * bf2f(t0_.u[jj]); \
    _Pragma("unroll") for (int jj = 0; jj < 8; ++jj) p_ += qv[8 + jj] * bf2f(t1_.u[jj]); \
    p_ += __shfl_xor(p_, 1); p_ += __shfl_xor(p_, 2); \
    if ((tid & 3) == 0) Sstr[sr][kk] = p_ * 0.125f + Ms; }
#define VISSUE(As, Bs, idx) { const ushort* vr_ = v_ws + srbase + ((size_t)(idx) << 13); \
    As = *(const uint4*)vr_; Bs = *(const uint4*)(vr_ + 8); }
#define VCONS(As, Bs, kk) { float p_ = Sstr[sr][kk]; union { uint4 v; ushort u[8]; } t0_, t1_; \
    t0_.v = As; t1_.v = Bs; \
    _Pragma("unroll") for (int jj = 0; jj < 8; ++jj) acc16[jj] += p_ * bf2f(t0_.u[jj]); \
    _Pragma("unroll") for (int jj = 0; jj < 8; ++jj) acc16[8 + jj] += p_ * bf2f(t1_.u[jj]); }

// ---------------------------------------------------------------------------
// Kernel 3: MFMA fused sparse attention v5 (unchanged from R4) — register-
// pressure-scoped to fit the (512,4) 128-VGPR cap without scratch spill.
// ---------------------------------------------------------------------------
__global__ __launch_bounds__(512, 4) void attn(
    const ushort* __restrict__ q_ws, const ushort* __restrict__ v_ws,
    const float* __restrict__ amask, float* __restrict__ out) {
    const int wg = blockIdx.x;           // 0..511
    const int half = wg >> 8, r5 = wg & 255;
    const int t_raw = r5 & 15;
    const int t = half ? (15 - t_raw) : t_raw;
    const int h = r5 >> 4;
    const int b = half;

    __shared__ ushort KwPl[16384];   // Kw 256x64 (swz) -> later P-half 128x128 (swz)
    __shared__ ushort VtS[16384];    // V^T 64x256 (swz) -> later ctxp 128x64 fp32 (swz)
    __shared__ float  Sstr[128][17]; // strided scores -> probs
    __shared__ float  amw[256];      // window slice of attention_mask

    const int tid = threadIdx.x;     // 0..511
    const int wid = tid >> 6, lane = tid & 63;
    const int quad = lane >> 4, l16 = lane & 15;
    const int r0 = wid * 16;
    const size_t qbase = ((size_t)b * 16 + h) * 2048 * 64;
    const int base_row = (t - 1) * 128;
    const int nk = (t >= 2) ? (t - 1) : 0;

    const int sr = tid >> 2;             // 0..127
    const int dq = (tid & 3) * 16;
    const size_t srbase = qbase + (size_t)sr * 64 + dq;
    const size_t amrow  = (size_t)b * 2048 + sr;

    // ---- (1) K-window async gload: LDS linear dest, inverse-swizzled source
#pragma unroll
    for (int i = 0; i < 4; ++i) {
        int u = tid + i * 512;               // 256 rows x 8 chunks
        int row = u >> 3, c = u & 7;
        int jg = base_row + row; if (jg < 0) jg = 0;
        int sc = c ^ (row & 7);
        gload_lds16(q_ws + qbase + (size_t)jg * 64 + sc * 8, &KwPl[u * 8]);
    }
    __builtin_amdgcn_sched_barrier(0);

    // ---- (2) V^T stage, write-immediate (4 uint4 regs live at a time)
    {
        const int vj = tid & 255, dh0 = (tid >> 8) * 32;
        int vjg = base_row + vj; if (vjg < 0) vjg = 0;
        const ushort* vsrc = v_ws + qbase + (size_t)vjg * 64 + dh0;
        int cj = vj >> 3, j7 = vj & 7;
#pragma unroll
        for (int d0 = 0; d0 < 32; d0 += 8) {
            union { uint4 v; ushort u[8]; } tmp;
            tmp.v = *(const uint4*)(vsrc + d0);
#pragma unroll
            for (int jj = 0; jj < 8; ++jj) {
                int dd = dh0 + d0 + jj;
                VtS[dd * 256 + ((cj ^ (dd & 7)) * 8) + j7] = tmp.u[jj];
            }
        }
        int amj = base_row + (tid & 255); if (amj < 0) amj = 0;
        amw[tid & 255] = amask[(size_t)b * 2048 + amj];
    }

    // ---- (3) pre-issue first strided-K slots (complete during the drain)
    uint4 kA0{}, kB0{}, kA1{}, kB1{}, kA2{}, kB2{};
    float am0 = 0.f, am1 = 0.f, am2 = 0.f;
    if (nk > 0) {
        SISSUE(kA0, kB0, am0, 0);
        SISSUE(kA1, kB1, am1, (1 < nk ? 1 : 0));
        SISSUE(kA2, kB2, am2, (2 < nk ? 2 : 0));
    }

    asm volatile("s_waitcnt vmcnt(0) lgkmcnt(0)" ::: "memory");
    __builtin_amdgcn_s_barrier();
    __builtin_amdgcn_sched_barrier(0);

    // ---- (4) strided scores BEFORE QK^T (sacc not yet live) ----
    if (nk > 0) {
        float qv[16];
#pragma unroll
        for (int cc = 0; cc < 2; ++cc) {
            int c = (dq >> 3) + cc;
            union { uint4 v; ushort u[8]; } tm;
            tm.v = *(const uint4*)&KwPl[(128 + sr) * 64 + ((c ^ (sr & 7)) * 8)];
#pragma unroll
            for (int jj = 0; jj < 8; ++jj) qv[cc * 8 + jj] = bf2f(tm.u[jj]);
        }
        for (int k = 0; k < nk; k += 3) {
            SCONS(kA0, kB0, am0, k);
            if (k + 3 < nk) SISSUE(kA0, kB0, am0, k + 3);
            if (k + 1 < nk) {
                SCONS(kA1, kB1, am1, k + 1);
                if (k + 4 < nk) SISSUE(kA1, kB1, am1, k + 4);
            }
            if (k + 2 < nk) {
                SCONS(kA2, kB2, am2, k + 2);
                if (k + 5 < nk) SISSUE(kA2, kB2, am2, k + 5);
            }
        }
    }

    // ---- (5) QK^T: wave -> rows [r0,r0+16) x 256 cols ----
    float4v sacc[16] = {};
    __builtin_amdgcn_s_setprio(1);
#pragma unroll
    for (int ks = 0; ks < 2; ++ks) {
        int c = ks * 4 + quad;
        int sw = (c ^ (l16 & 7)) * 8;
        short8 af = *(const short8*)&KwPl[(128 + r0 + l16) * 64 + sw];
#pragma unroll
        for (int nt = 0; nt < 16; ++nt) {
            short8 bfr = *(const short8*)&KwPl[(nt * 16 + l16) * 64 + sw];
            sacc[nt] = __builtin_amdgcn_mfma_f32_16x16x32_bf16(af, bfr, sacc[nt], 0, 0, 0);
        }
    }
    __builtin_amdgcn_s_setprio(0);
    __syncthreads();   // Kw reads done (MFMA + qv); Sstr written; region -> P

    // ---- softmax (exp overlaid into sacc); write P-half1, stash half2 ----
    unsigned pb[4][4];
#pragma unroll
    for (int reg = 0; reg < 4; ++reg) {
        int rr = r0 + quad * 4 + reg;
        float sstr_v = (l16 < nk) ? Sstr[rr][l16] : -INFINITY;
        float m = sstr_v;
#pragma unroll
        for (int nt = 0; nt < 16; ++nt) {
            int c = nt * 16 + l16;
            bool allowed = (c >= rr) && (c <= rr + 128) && (t > 0 || c >= 128);
            float x = allowed ? sacc[nt][reg] * 0.125f + amw[c] : -INFINITY;
            sacc[nt][reg] = x;
            m = fmaxf(m, x);
        }
#pragma unroll
        for (int off = 1; off < 16; off <<= 1) m = fmaxf(m, __shfl_xor(m, off));

        float es = (l16 < nk) ? __expf(sstr_v - m) : 0.f;
        float sum = es;
#pragma unroll
        for (int nt = 0; nt < 16; ++nt) {
            float x = sacc[nt][reg];
            float e = (x == -INFINITY) ? 0.f : __expf(x - m);
            sacc[nt][reg] = e; sum += e;
        }
#pragma unroll
        for (int off = 1; off < 16; off <<= 1) sum += __shfl_xor(sum, off);
        float rden = 1.f / sum;
#pragma unroll
        for (int nt = 0; nt < 8; ++nt) {
            int c = nt * 2 + (l16 >> 3);
            KwPl[rr * 128 + ((c ^ (rr & 15)) * 8) + (l16 & 7)] = f2bf(sacc[nt][reg] * rden);
        }
#pragma unroll
        for (int i2 = 0; i2 < 4; ++i2) {
            unsigned lo = f2bf(sacc[8 + 2 * i2][reg] * rden);
            unsigned hi = f2bf(sacc[9 + 2 * i2][reg] * rden);
            pb[reg][i2] = lo | (hi << 16);
        }
        if (l16 < nk) Sstr[rr][l16] = es * rden;
    }
    __syncthreads();

    // ---- strided-V slot prefetch: latency covered by PV1/P2/PV2 ----
    uint4 vA0{}, vB0{}, vA1{}, vB1{}, vA2{}, vB2{};
    if (nk > 0) {
        VISSUE(vA0, vB0, 0);
        VISSUE(vA1, vB1, (1 < nk ? 1 : 0));
        VISSUE(vA2, vB2, (2 < nk ? 2 : 0));
    }

    // ---- PV pass 1: P(cols 0..127) x Vt(j 0..127) ----
    float4v cacc[4] = {};
    __builtin_amdgcn_s_setprio(1);
#pragma unroll
    for (int ks = 0; ks < 4; ++ks) {
        int cp = ks * 4 + quad;
        short8 af = *(const short8*)&KwPl[(r0 + l16) * 128 + ((cp ^ l16) * 8)];
#pragma unroll
        for (int nt = 0; nt < 4; ++nt) {
            int sw = (cp ^ (l16 & 7)) * 8;
            short8 bfr = *(const short8*)&VtS[(nt * 16 + l16) * 256 + sw];
            cacc[nt] = __builtin_amdgcn_mfma_f32_16x16x32_bf16(af, bfr, cacc[nt], 0, 0, 0);
        }
    }
    __builtin_amdgcn_s_setprio(0);
    __syncthreads();   // P-half1 reads done

    // ---- write P-half2 ----
#pragma unroll
    for (int reg = 0; reg < 4; ++reg) {
        int rr = r0 + quad * 4 + reg;
#pragma unroll
        for (int i2 = 0; i2 < 4; ++i2) {
            int nt0 = 8 + 2 * i2;
#pragma unroll
            for (int e2 = 0; e2 < 2; ++e2) {
                int nt = nt0 + e2;
                int c = (nt - 8) * 2 + (l16 >> 3);
                ushort val = (ushort)((pb[reg][i2] >> (16 * e2)) & 0xFFFF);
                KwPl[rr * 128 + ((c ^ (rr & 15)) * 8) + (l16 & 7)] = val;
            }
        }
    }
    __syncthreads();

    // ---- PV pass 2: P(cols 128..255) x Vt(j 128..255) ----
    __builtin_amdgcn_s_setprio(1);
#pragma unroll
    for (int ks = 0; ks < 4; ++ks) {
        int cp = ks * 4 + quad;
        short8 af = *(const short8*)&KwPl[(r0 + l16) * 128 + ((cp ^ l16) * 8)];
#pragma unroll
        for (int nt = 0; nt < 4; ++nt) {
            int cv = 16 + cp;
            int sw = (cv ^ (l16 & 7)) * 8;
            short8 bfr = *(const short8*)&VtS[(nt * 16 + l16) * 256 + sw];
            cacc[nt] = __builtin_amdgcn_mfma_f32_16x16x32_bf16(af, bfr, cacc[nt], 0, 0, 0);
        }
    }
    __builtin_amdgcn_s_setprio(0);

    // ---- strided PV: 3-deep rotation (before VtS is re-purposed) ----
    float acc16[16] = {};
    if (nk > 0) {
        for (int k = 0; k < nk; k += 3) {
            VCONS(vA0, vB0, k);
            if (k + 3 < nk) VISSUE(vA0, vB0, k + 3);
            if (k + 1 < nk) {
                VCONS(vA1, vB1, k + 1);
                if (k + 4 < nk) VISSUE(vA1, vB1, k + 4);
            }
            if (k + 2 < nk) {
                VCONS(vA2, vB2, k + 2);
                if (k + 5 < nk) VISSUE(vA2, vB2, k + 5);
            }
        }
    }
    __syncthreads();   // Vt reads done; region becomes ctxp

    float* ctxp = (float*)&VtS[0];   // [128][64] fp32, chunk-swizzled
#pragma unroll
    for (int d4 = 0; d4 < 4; ++d4) {
        int c = (dq >> 2) + d4;
        *(float4v*)&ctxp[sr * 64 + ((c ^ (sr & 15)) * 4)] =
            *(const float4v*)&acc16[d4 * 4];
    }
    __syncthreads();

    // ---- epilogue: out[b][s][h*64+d], fp32 ----
    const size_t obase = ((size_t)b * 2048 + (size_t)t * 128) * 1024 + (size_t)h * 64;
#pragma unroll
    for (int nt = 0; nt < 4; ++nt)
#pragma unroll
        for (int reg = 0; reg < 4; ++reg) {
            int rr = r0 + quad * 4 + reg;
            int d = nt * 16 + l16;
            float cstr = ctxp[rr * 64 + (((d >> 2) ^ (rr & 15)) * 4) + (d & 3)];
            out[obase + (size_t)rr * 1024 + d] = cacc[nt][reg] + cstr;
        }
}

// ---------------------------------------------------------------------------
extern "C" void kernel_launch(void* const* d_in, const int* in_sizes, int n_in,
                              void* d_out, int out_size, void* d_ws, size_t ws_size,
                              hipStream_t stream) {
    int ihs = -1, iam = -1, iw1 = -1, iw2 = -1, ib1 = -1, ib2 = -1;
    for (int i = 0; i < n_in; ++i) {
        int s = in_sizes[i];
        if      (s == 4194304) { if (ihs < 0) ihs = i; }
        else if (s == 4096)    { if (iam < 0) iam = i; }
        else if (s == 1048576) { if (iw1 < 0) iw1 = i; else if (iw2 < 0) iw2 = i; }
        else if (s == 1024)    { if (ib1 < 0) ib1 = i; else if (ib2 < 0) ib2 = i; }
    }
    if (ihs < 0) ihs = 0; if (iam < 0) iam = 1;
    if (iw1 < 0) iw1 = 2; if (ib1 < 0) ib1 = 3;
    if (iw2 < 0) iw2 = 4; if (ib2 < 0) ib2 = 5;

    const float* hs    = (const float*)d_in[ihs];
    const float* amask = (const float*)d_in[iam];
    const float* Wq    = (const float*)d_in[iw1];
    const float* bq    = (const float*)d_in[ib1];
    const float* Wv    = (const float*)d_in[iw2];
    const float* bv    = (const float*)d_in[ib2];
    float* out = (float*)d_out;

    char* ws = (char*)d_ws;
    ushort* Wt   = (ushort*)(ws);                            // 4 MB fused [2048][1024]
    ushort* hsb  = (ushort*)(ws + (1u << 22));               // 8 MB
    ushort* q_ws = (ushort*)(ws + (1u << 22) + (1u << 23));  // 8 MB
    ushort* v_ws = (ushort*)(ws + (1u << 22) + (2u << 23));  // 8 MB

    prep<<<1536, 256, 0, stream>>>(hs, hsb, Wq, Wv, Wt);
    qv_gemm<<<256, 512, 0, stream>>>(hsb, Wt, bq, bv, q_ws, v_ws);
    attn<<<512, 512, 0, stream>>>(q_ws, v_ws, amask, out);
}

// Round 6
// 131.363 us; speedup vs baseline: 1.0509x; 1.0509x over previous
//
#include <hip/hip_runtime.h>

typedef __attribute__((ext_vector_type(8))) short short8;
typedef __attribute__((ext_vector_type(4))) float float4v;

__device__ inline float bf2f(ushort u) {
    unsigned v = ((unsigned)u) << 16;
    return __builtin_bit_cast(float, v);
}
__device__ inline ushort f2bf(float f) {
    unsigned u = __builtin_bit_cast(unsigned, f);
    u += 0x7FFFu + ((u >> 16) & 1u);   // RNE
    return (ushort)(u >> 16);
}

// async global->LDS, 16B per lane; LDS dest = wave-uniform base + lane*16
__device__ inline void gload_lds16(const ushort* g, ushort* l) {
    __builtin_amdgcn_global_load_lds(
        (const __attribute__((address_space(1))) unsigned int*)g,
        (__attribute__((address_space(3))) unsigned int*)l,
        16, 0, 0);
}

// ---------------------------------------------------------------------------
// Kernel 1: prep = convert_hs (blocks 0..1023) + transpose_w (blocks 1024..1535)
// ---------------------------------------------------------------------------
__global__ __launch_bounds__(256) void prep(
    const float* __restrict__ hs, ushort* __restrict__ hsb,
    const float* __restrict__ Wq, const float* __restrict__ Wv,
    ushort* __restrict__ Wt) {
    __shared__ ushort tile[64][68];
    if (blockIdx.x < 1024) {
        const size_t base = ((size_t)blockIdx.x * 256 + threadIdx.x) * 16;
        union { ushort u[16]; uint4 v[2]; } o;
#pragma unroll
        for (int q = 0; q < 4; ++q) {
            float4v f = *(const float4v*)(hs + base + q * 4);
#pragma unroll
            for (int j = 0; j < 4; ++j) o.u[q * 4 + j] = f2bf(f[j]);
        }
        *(uint4*)(hsb + base)     = o.v[0];
        *(uint4*)(hsb + base + 8) = o.v[1];
        return;
    }
    const int idx = blockIdx.x - 1024;
    const int z = idx >> 8, yy = (idx >> 4) & 15, xx = idx & 15;
    const float* W = z ? Wv : Wq;
    ushort* Wto    = Wt + (z ? (size_t)1024 * 1024 : 0);
    const int k0 = yy * 64, n0 = xx * 64;
    const int tid = threadIdx.x;
    const int rr = tid >> 4;          // 0..15
    const int cc = (tid & 15) * 4;    // 0..60
    union U4 { ushort u[4]; uint2 v; };
#pragma unroll
    for (int i = 0; i < 4; ++i) {
        int row = rr + i * 16;
        float4v f = *(const float4v*)(W + (size_t)(k0 + row) * 1024 + n0 + cc);
        U4 x;
#pragma unroll
        for (int j = 0; j < 4; ++j) x.u[j] = f2bf(f[j]);
        *(uint2*)&tile[row][cc] = x.v;
    }
    __syncthreads();
#pragma unroll
    for (int i = 0; i < 4; ++i) {
        int row = rr + i * 16;        // n within tile
        U4 o;
#pragma unroll
        for (int j = 0; j < 4; ++j) o.u[j] = tile[cc + j][row];
        *(uint2*)(Wto + (size_t)(n0 + row) * 1024 + k0 + cc) = o.v;
    }
}

// ---------------------------------------------------------------------------
// Kernel 2: fused Q|V GEMM (R4 winner, reverted from the 4-phase experiment).
// 1-barrier K-loop + counted vmcnt + XCD-aware block remap.
// ---------------------------------------------------------------------------
__global__ __launch_bounds__(512, 2) void qv_gemm(
    const ushort* __restrict__ hsb, const ushort* __restrict__ Wt,
    const float* __restrict__ bq, const float* __restrict__ bv,
    ushort* __restrict__ q_ws, ushort* __restrict__ v_ws) {
    __shared__ ushort smem[73728];                 // 3 * 49152 B
    const int wg = blockIdx.x;                     // 0..255
    const int n0 = (wg & 7) * 256;                 // XCD id (round-robin) -> B panel
    const int m0 = (wg >> 3) * 128;
    const int tid  = threadIdx.x;
    const int wid  = tid >> 6, lane = tid & 63;
    const int quad = lane >> 4, l16 = lane & 15;
    const int wm = (wid >> 2) * 64;                // 0 / 64
    const int wn = (wid & 3) * 64;                 // 0 / 64 / 128 / 192
    const int srow8 = tid >> 3;                    // 0..63 (rows per 8KB round)
    const int scb   = (tid & 7) * 16;              // phys chunk byte 0..112

    auto stage = [&](int ktt, int bi, int r) {
        if (r < 2) {
            int row = r * 64 + srow8;                       // A row 0..127
            int sb  = scb ^ ((row & 7) << 4);               // inverse swizzle
            gload_lds16(hsb + (size_t)(m0 + row) * 1024 + ktt * 64 + (sb >> 1),
                        (ushort*)((char*)smem + bi * 49152 + r * 8192 + wid * 1024));
        } else {
            int row = (r - 2) * 64 + srow8;                 // B row 0..255
            int sb  = scb ^ ((row & 7) << 4);
            gload_lds16(Wt + (size_t)(n0 + row) * 1024 + ktt * 64 + (sb >> 1),
                        (ushort*)((char*)smem + bi * 49152 + 16384 + (r - 2) * 8192 + wid * 1024));
        }
    };

    float4v acc[4][4] = {};

#pragma unroll
    for (int r = 0; r < 6; ++r) stage(0, 0, r);
#pragma unroll
    for (int r = 0; r < 6; ++r) stage(1, 1, r);

    int bi = 0;
    for (int ktt = 0; ktt < 16; ++ktt) {
        const char* Ab = (const char*)smem + bi * 49152;
        const char* Bb = Ab + 16384;

        if (ktt < 15) asm volatile("s_waitcnt vmcnt(6)" ::: "memory");
        else          asm volatile("s_waitcnt vmcnt(0)" ::: "memory");
        __builtin_amdgcn_s_barrier();
        __builtin_amdgcn_sched_barrier(0);

        short8 af[4][2], bfr[4][2];
#pragma unroll
        for (int mt = 0; mt < 4; ++mt) {
            int ar = wm + mt * 16 + l16;
            int sw = (ar & 7) << 4;
            af[mt][0] = *(const short8*)(Ab + ar * 128 + ((quad * 16) ^ sw));
        }
#pragma unroll
        for (int nt = 0; nt < 4; ++nt) {
            int br = wn + nt * 16 + l16;
            int sw = (br & 7) << 4;
            bfr[nt][0] = *(const short8*)(Bb + br * 128 + ((quad * 16) ^ sw));
        }
        __builtin_amdgcn_sched_barrier(0);
        const int kn = ktt + 2;
        const int b2 = (bi + 2 >= 3) ? bi - 1 : bi + 2;
        if (kn < 16) {
            stage(kn, b2, 0); stage(kn, b2, 1); stage(kn, b2, 2);
            stage(kn, b2, 3); stage(kn, b2, 4); stage(kn, b2, 5);
        }
#pragma unroll
        for (int mt = 0; mt < 4; ++mt) {
            int ar = wm + mt * 16 + l16;
            int sw = (ar & 7) << 4;
            af[mt][1] = *(const short8*)(Ab + ar * 128 + (((4 + quad) * 16) ^ sw));
        }
#pragma unroll
        for (int nt = 0; nt < 4; ++nt) {
            int br = wn + nt * 16 + l16;
            int sw = (br & 7) << 4;
            bfr[nt][1] = *(const short8*)(Bb + br * 128 + (((4 + quad) * 16) ^ sw));
        }
        __builtin_amdgcn_sched_barrier(0);
        asm volatile("s_waitcnt lgkmcnt(8)" ::: "memory");
        __builtin_amdgcn_sched_barrier(0);
        __builtin_amdgcn_s_setprio(1);
#pragma unroll
        for (int mt = 0; mt < 4; ++mt)
#pragma unroll
            for (int nt = 0; nt < 4; ++nt)
                acc[mt][nt] = __builtin_amdgcn_mfma_f32_16x16x32_bf16(
                    af[mt][0], bfr[nt][0], acc[mt][nt], 0, 0, 0);
        __builtin_amdgcn_s_setprio(0);
        asm volatile("s_waitcnt lgkmcnt(0)" ::: "memory");
        __builtin_amdgcn_sched_barrier(0);
        __builtin_amdgcn_s_setprio(1);
#pragma unroll
        for (int mt = 0; mt < 4; ++mt)
#pragma unroll
            for (int nt = 0; nt < 4; ++nt)
                acc[mt][nt] = __builtin_amdgcn_mfma_f32_16x16x32_bf16(
                    af[mt][1], bfr[nt][1], acc[mt][nt], 0, 0, 0);
        __builtin_amdgcn_s_setprio(0);

        bi = (bi + 1 >= 3) ? 0 : bi + 1;
    }

#pragma unroll
    for (int mt = 0; mt < 4; ++mt) {
#pragma unroll
        for (int nt = 0; nt < 4; ++nt) {
            int coln = n0 + wn + nt * 16 + l16;
            bool isq = coln < 1024;
            int c2 = isq ? coln : coln - 1024;
            float bsv = isq ? bq[c2] : bv[c2];
            ushort* outp = isq ? q_ws : v_ws;
            int hh = c2 >> 6, dd = c2 & 63;
#pragma unroll
            for (int reg = 0; reg < 4; ++reg) {
                int r = m0 + wm + mt * 16 + quad * 4 + reg;
                int bb = r >> 11, s = r & 2047;
                outp[(((size_t)bb * 16 + hh) * 2048 + s) * 64 + dd] =
                    f2bf(acc[mt][nt][reg] + bsv);
            }
        }
    }
}

// strided-loop slot macros (static register slots, rule #20)
#define SISSUE(As, Bs, Ms, idx) { const ushort* kr_ = q_ws + srbase + ((size_t)(idx) << 13); \
    As = *(const uint4*)kr_; Bs = *(const uint4*)(kr_ + 8); Ms = amask[amrow + ((idx) << 7)]; }
#define SCONS(As, Bs, Ms, kk) { union { uint4 v; ushort u[8]; } t0_, t1_; t0_.v = As; t1_.v = Bs; \
    float p_ = 0.f; \
    _Pragma("unroll") for (int jj = 0; jj < 8; ++jj) p_ += qv[jj] * bf2f(t0_.u[jj]); \
    _Pragma("unroll") for (int jj = 0; jj < 8; ++jj) p_ += qv[8 + jj] * bf2f(t1_.u[jj]); \
    p_ += __shfl_xor(p_, 1); p_ += __shfl_xor(p_, 2); \
    if ((tid & 3) == 0) Sstr[sr][kk] = p_ * 0.125f + Ms; }
#define VISSUE(As, Bs, idx) { const ushort* vr_ = v_ws + srbase + ((size_t)(idx) << 13); \
    As = *(const uint4*)vr_; Bs = *(const uint4*)(vr_ + 8); }
#define VCONS(As, Bs, kk) { float p_ = Sstr[sr][kk]; union { uint4 v; ushort u[8]; } t0_, t1_; \
    t0_.v = As; t1_.v = Bs; \
    _Pragma("unroll") for (int jj = 0; jj < 8; ++jj) acc16[jj] += p_ * bf2f(t0_.u[jj]); \
    _Pragma("unroll") for (int jj = 0; jj < 8; ++jj) acc16[8 + jj] += p_ * bf2f(t1_.u[jj]); }

// ---------------------------------------------------------------------------
// Kernel 3: MFMA fused sparse attention v6 = R4's v5 + XCD-affinity remap:
//  all 16 t-blocks of a (b,h) land on ONE XCD (wg&7 = XCD lane), 4 groups
//  per XCD (2MB K+V resident in 4MB L2) -> strided gathers (~215MB, 14x
//  re-read within a group) become L2 hits instead of L3/HBM. Within an
//  XCD, CU's two co-resident blocks carry t and 15-t (balanced gathers).
// ---------------------------------------------------------------------------
__global__ __launch_bounds__(512, 4) void attn(
    const ushort* __restrict__ q_ws, const ushort* __restrict__ v_ws,
    const float* __restrict__ amask, float* __restrict__ out) {
    const int wg = blockIdx.x;           // 0..511
    const int lane8 = wg & 7;            // XCD lane
    const int k8    = wg >> 3;           // 0..63
    const int kk    = k8 & 31, khalf = k8 >> 5;
    const int t  = khalf ? (15 - (kk & 15)) : (kk & 15);
    const int gq = (kk >> 4) + 2 * khalf;           // 0..3
    const int g  = gq * 8 + lane8;                  // 0..31 = b*16+h
    const int b  = g >> 4;
    const int h  = g & 15;

    __shared__ ushort KwPl[16384];   // Kw 256x64 (swz) -> later P-half 128x128 (swz)
    __shared__ ushort VtS[16384];    // V^T 64x256 (swz) -> later ctxp 128x64 fp32 (swz)
    __shared__ float  Sstr[128][17]; // strided scores -> probs
    __shared__ float  amw[256];      // window slice of attention_mask

    const int tid = threadIdx.x;     // 0..511
    const int wid = tid >> 6, lane = tid & 63;
    const int quad = lane >> 4, l16 = lane & 15;
    const int r0 = wid * 16;
    const size_t qbase = ((size_t)b * 16 + h) * 2048 * 64;
    const int base_row = (t - 1) * 128;
    const int nk = (t >= 2) ? (t - 1) : 0;

    const int sr = tid >> 2;             // 0..127
    const int dq = (tid & 3) * 16;
    const size_t srbase = qbase + (size_t)sr * 64 + dq;
    const size_t amrow  = (size_t)b * 2048 + sr;

    // ---- (1) K-window async gload: LDS linear dest, inverse-swizzled source
#pragma unroll
    for (int i = 0; i < 4; ++i) {
        int u = tid + i * 512;               // 256 rows x 8 chunks
        int row = u >> 3, c = u & 7;
        int jg = base_row + row; if (jg < 0) jg = 0;
        int sc = c ^ (row & 7);
        gload_lds16(q_ws + qbase + (size_t)jg * 64 + sc * 8, &KwPl[u * 8]);
    }
    __builtin_amdgcn_sched_barrier(0);

    // ---- (2) V^T stage, write-immediate (4 uint4 regs live at a time)
    {
        const int vj = tid & 255, dh0 = (tid >> 8) * 32;
        int vjg = base_row + vj; if (vjg < 0) vjg = 0;
        const ushort* vsrc = v_ws + qbase + (size_t)vjg * 64 + dh0;
        int cj = vj >> 3, j7 = vj & 7;
#pragma unroll
        for (int d0 = 0; d0 < 32; d0 += 8) {
            union { uint4 v; ushort u[8]; } tmp;
            tmp.v = *(const uint4*)(vsrc + d0);
#pragma unroll
            for (int jj = 0; jj < 8; ++jj) {
                int dd = dh0 + d0 + jj;
                VtS[dd * 256 + ((cj ^ (dd & 7)) * 8) + j7] = tmp.u[jj];
            }
        }
        int amj = base_row + (tid & 255); if (amj < 0) amj = 0;
        amw[tid & 255] = amask[(size_t)b * 2048 + amj];
    }

    // ---- (3) pre-issue first strided-K slots (complete during the drain)
    uint4 kA0{}, kB0{}, kA1{}, kB1{}, kA2{}, kB2{};
    float am0 = 0.f, am1 = 0.f, am2 = 0.f;
    if (nk > 0) {
        SISSUE(kA0, kB0, am0, 0);
        SISSUE(kA1, kB1, am1, (1 < nk ? 1 : 0));
        SISSUE(kA2, kB2, am2, (2 < nk ? 2 : 0));
    }

    asm volatile("s_waitcnt vmcnt(0) lgkmcnt(0)" ::: "memory");
    __builtin_amdgcn_s_barrier();
    __builtin_amdgcn_sched_barrier(0);

    // ---- (4) strided scores BEFORE QK^T (sacc not yet live) ----
    if (nk > 0) {
        float qv[16];
#pragma unroll
        for (int cc = 0; cc < 2; ++cc) {
            int c = (dq >> 3) + cc;
            union { uint4 v; ushort u[8]; } tm;
            tm.v = *(const uint4*)&KwPl[(128 + sr) * 64 + ((c ^ (sr & 7)) * 8)];
#pragma unroll
            for (int jj = 0; jj < 8; ++jj) qv[cc * 8 + jj] = bf2f(tm.u[jj]);
        }
        for (int k = 0; k < nk; k += 3) {
            SCONS(kA0, kB0, am0, k);
            if (k + 3 < nk) SISSUE(kA0, kB0, am0, k + 3);
            if (k + 1 < nk) {
                SCONS(kA1, kB1, am1, k + 1);
                if (k + 4 < nk) SISSUE(kA1, kB1, am1, k + 4);
            }
            if (k + 2 < nk) {
                SCONS(kA2, kB2, am2, k + 2);
                if (k + 5 < nk) SISSUE(kA2, kB2, am2, k + 5);
            }
        }
    }

    // ---- (5) QK^T: wave -> rows [r0,r0+16) x 256 cols ----
    float4v sacc[16] = {};
    __builtin_amdgcn_s_setprio(1);
#pragma unroll
    for (int ks = 0; ks < 2; ++ks) {
        int c = ks * 4 + quad;
        int sw = (c ^ (l16 & 7)) * 8;
        short8 af = *(const short8*)&KwPl[(128 + r0 + l16) * 64 + sw];
#pragma unroll
        for (int nt = 0; nt < 16; ++nt) {
            short8 bfr = *(const short8*)&KwPl[(nt * 16 + l16) * 64 + sw];
            sacc[nt] = __builtin_amdgcn_mfma_f32_16x16x32_bf16(af, bfr, sacc[nt], 0, 0, 0);
        }
    }
    __builtin_amdgcn_s_setprio(0);
    __syncthreads();   // Kw reads done (MFMA + qv); Sstr written; region -> P

    // ---- softmax (exp overlaid into sacc); write P-half1, stash half2 ----
    unsigned pb[4][4];
#pragma unroll
    for (int reg = 0; reg < 4; ++reg) {
        int rr = r0 + quad * 4 + reg;
        float sstr_v = (l16 < nk) ? Sstr[rr][l16] : -INFINITY;
        float m = sstr_v;
#pragma unroll
        for (int nt = 0; nt < 16; ++nt) {
            int c = nt * 16 + l16;
            bool allowed = (c >= rr) && (c <= rr + 128) && (t > 0 || c >= 128);
            float x = allowed ? sacc[nt][reg] * 0.125f + amw[c] : -INFINITY;
            sacc[nt][reg] = x;
            m = fmaxf(m, x);
        }
#pragma unroll
        for (int off = 1; off < 16; off <<= 1) m = fmaxf(m, __shfl_xor(m, off));

        float es = (l16 < nk) ? __expf(sstr_v - m) : 0.f;
        float sum = es;
#pragma unroll
        for (int nt = 0; nt < 16; ++nt) {
            float x = sacc[nt][reg];
            float e = (x == -INFINITY) ? 0.f : __expf(x - m);
            sacc[nt][reg] = e; sum += e;
        }
#pragma unroll
        for (int off = 1; off < 16; off <<= 1) sum += __shfl_xor(sum, off);
        float rden = 1.f / sum;
#pragma unroll
        for (int nt = 0; nt < 8; ++nt) {
            int c = nt * 2 + (l16 >> 3);
            KwPl[rr * 128 + ((c ^ (rr & 15)) * 8) + (l16 & 7)] = f2bf(sacc[nt][reg] * rden);
        }
#pragma unroll
        for (int i2 = 0; i2 < 4; ++i2) {
            unsigned lo = f2bf(sacc[8 + 2 * i2][reg] * rden);
            unsigned hi = f2bf(sacc[9 + 2 * i2][reg] * rden);
            pb[reg][i2] = lo | (hi << 16);
        }
        if (l16 < nk) Sstr[rr][l16] = es * rden;
    }
    __syncthreads();

    // ---- strided-V slot prefetch: latency covered by PV1/P2/PV2 ----
    uint4 vA0{}, vB0{}, vA1{}, vB1{}, vA2{}, vB2{};
    if (nk > 0) {
        VISSUE(vA0, vB0, 0);
        VISSUE(vA1, vB1, (1 < nk ? 1 : 0));
        VISSUE(vA2, vB2, (2 < nk ? 2 : 0));
    }

    // ---- PV pass 1: P(cols 0..127) x Vt(j 0..127) ----
    float4v cacc[4] = {};
    __builtin_amdgcn_s_setprio(1);
#pragma unroll
    for (int ks = 0; ks < 4; ++ks) {
        int cp = ks * 4 + quad;
        short8 af = *(const short8*)&KwPl[(r0 + l16) * 128 + ((cp ^ l16) * 8)];
#pragma unroll
        for (int nt = 0; nt < 4; ++nt) {
            int sw = (cp ^ (l16 & 7)) * 8;
            short8 bfr = *(const short8*)&VtS[(nt * 16 + l16) * 256 + sw];
            cacc[nt] = __builtin_amdgcn_mfma_f32_16x16x32_bf16(af, bfr, cacc[nt], 0, 0, 0);
        }
    }
    __builtin_amdgcn_s_setprio(0);
    __syncthreads();   // P-half1 reads done

    // ---- write P-half2 ----
#pragma unroll
    for (int reg = 0; reg < 4; ++reg) {
        int rr = r0 + quad * 4 + reg;
#pragma unroll
        for (int i2 = 0; i2 < 4; ++i2) {
            int nt0 = 8 + 2 * i2;
#pragma unroll
            for (int e2 = 0; e2 < 2; ++e2) {
                int nt = nt0 + e2;
                int c = (nt - 8) * 2 + (l16 >> 3);
                ushort val = (ushort)((pb[reg][i2] >> (16 * e2)) & 0xFFFF);
                KwPl[rr * 128 + ((c ^ (rr & 15)) * 8) + (l16 & 7)] = val;
            }
        }
    }
    __syncthreads();

    // ---- PV pass 2: P(cols 128..255) x Vt(j 128..255) ----
    __builtin_amdgcn_s_setprio(1);
#pragma unroll
    for (int ks = 0; ks < 4; ++ks) {
        int cp = ks * 4 + quad;
        short8 af = *(const short8*)&KwPl[(r0 + l16) * 128 + ((cp ^ l16) * 8)];
#pragma unroll
        for (int nt = 0; nt < 4; ++nt) {
            int cv = 16 + cp;
            int sw = (cv ^ (l16 & 7)) * 8;
            short8 bfr = *(const short8*)&VtS[(nt * 16 + l16) * 256 + sw];
            cacc[nt] = __builtin_amdgcn_mfma_f32_16x16x32_bf16(af, bfr, cacc[nt], 0, 0, 0);
        }
    }
    __builtin_amdgcn_s_setprio(0);

    // ---- strided PV: 3-deep rotation (before VtS is re-purposed) ----
    float acc16[16] = {};
    if (nk > 0) {
        for (int k = 0; k < nk; k += 3) {
            VCONS(vA0, vB0, k);
            if (k + 3 < nk) VISSUE(vA0, vB0, k + 3);
            if (k + 1 < nk) {
                VCONS(vA1, vB1, k + 1);
                if (k + 4 < nk) VISSUE(vA1, vB1, k + 4);
            }
            if (k + 2 < nk) {
                VCONS(vA2, vB2, k + 2);
                if (k + 5 < nk) VISSUE(vA2, vB2, k + 5);
            }
        }
    }
    __syncthreads();   // Vt reads done; region becomes ctxp

    float* ctxp = (float*)&VtS[0];   // [128][64] fp32, chunk-swizzled
#pragma unroll
    for (int d4 = 0; d4 < 4; ++d4) {
        int c = (dq >> 2) + d4;
        *(float4v*)&ctxp[sr * 64 + ((c ^ (sr & 15)) * 4)] =
            *(const float4v*)&acc16[d4 * 4];
    }
    __syncthreads();

    // ---- epilogue: out[b][s][h*64+d], fp32 ----
    const size_t obase = ((size_t)b * 2048 + (size_t)t * 128) * 1024 + (size_t)h * 64;
#pragma unroll
    for (int nt = 0; nt < 4; ++nt)
#pragma unroll
        for (int reg = 0; reg < 4; ++reg) {
            int rr = r0 + quad * 4 + reg;
            int d = nt * 16 + l16;
            float cstr = ctxp[rr * 64 + (((d >> 2) ^ (rr & 15)) * 4) + (d & 3)];
            out[obase + (size_t)rr * 1024 + d] = cacc[nt][reg] + cstr;
        }
}

// ---------------------------------------------------------------------------
extern "C" void kernel_launch(void* const* d_in, const int* in_sizes, int n_in,
                              void* d_out, int out_size, void* d_ws, size_t ws_size,
                              hipStream_t stream) {
    int ihs = -1, iam = -1, iw1 = -1, iw2 = -1, ib1 = -1, ib2 = -1;
    for (int i = 0; i < n_in; ++i) {
        int s = in_sizes[i];
        if      (s == 4194304) { if (ihs < 0) ihs = i; }
        else if (s == 4096)    { if (iam < 0) iam = i; }
        else if (s == 1048576) { if (iw1 < 0) iw1 = i; else if (iw2 < 0) iw2 = i; }
        else if (s == 1024)    { if (ib1 < 0) ib1 = i; else if (ib2 < 0) ib2 = i; }
    }
    if (ihs < 0) ihs = 0; if (iam < 0) iam = 1;
    if (iw1 < 0) iw1 = 2; if (ib1 < 0) ib1 = 3;
    if (iw2 < 0) iw2 = 4; if (ib2 < 0) ib2 = 5;

    const float* hs    = (const float*)d_in[ihs];
    const float* amask = (const float*)d_in[iam];
    const float* Wq    = (const float*)d_in[iw1];
    const float* bq    = (const float*)d_in[ib1];
    const float* Wv    = (const float*)d_in[iw2];
    const float* bv    = (const float*)d_in[ib2];
    float* out = (float*)d_out;

    char* ws = (char*)d_ws;
    ushort* Wt   = (ushort*)(ws);                            // 4 MB fused [2048][1024]
    ushort* hsb  = (ushort*)(ws + (1u << 22));               // 8 MB
    ushort* q_ws = (ushort*)(ws + (1u << 22) + (1u << 23));  // 8 MB
    ushort* v_ws = (ushort*)(ws + (1u << 22) + (2u << 23));  // 8 MB

    prep<<<1536, 256, 0, stream>>>(hs, hsb, Wq, Wv, Wt);
    qv_gemm<<<256, 512, 0, stream>>>(hsb, Wt, bq, bv, q_ws, v_ws);
    attn<<<512, 512, 0, stream>>>(q_ws, v_ws, amask, out);
}